// Round 19
// baseline (70.389 us; speedup 1.0000x reference)
//
#include <hip/hip_runtime.h>
#include <math.h>

#pragma clang fp contract(off)

// ---------------------------------------------------------------------------
// Bit-exact fp32 emulation of the XLA-CPU (reassoc+contract) reference
// realization — PASSING since r10 (absmax 0.1875, bit-stable r10-r18).
// Per-step value tree (unchanged since r10):
//   u = fadd( fma(s3,a1, mul(s2,b2)), fma(s1,a3, -w) ),
//   w = Markstein(n=mul(s0,d4), d, y2),  y2 = rcp+2xNewton(d)  [VCC-free CR]
// r18 analysis: wave issues ~70% of cycles; the residual stall is the spine's
// dependent chain with nothing to overlap (next group's MKC work sits across
// the loop boundary). This round: unified backward loop with depth-1 explicit
// software pipeline — per iteration: load group g+2, MKC group g+1 (40
// independent ops), WC+spine group g, panel-accumulate (descending order,
// validated r16-r18). Same op set, reordered => identical bits.
// ---------------------------------------------------------------------------

__device__ __forceinline__ float fmul32(float a, float b) { return a * b; }
__device__ __forceinline__ float fadd32(float a, float b) { return a + b; }
__device__ __forceinline__ float fsub32(float a, float b) { return a - b; }
#define FMA32(a, b, c) __builtin_fmaf((a), (b), (c))

struct Coef { float a, bc, d, y2; };

__global__ __launch_bounds__(64, 1)
void eval_eig_kernel(const float* __restrict__ ein, float* __restrict__ out, int ntot) {
  constexpr double RD64  = 100.0 / 1000.0;
  constexpr double RD2   = RD64 * RD64;
  constexpr float  KA32  = (float)(13.0 / 15.0 * RD2);
  constexpr float  KB32  = (float)( 7.0 / 60.0 * RD2);
  constexpr float  KC32  = (float)( 3.0 / 40.0 * RD2);
  constexpr float  nKC32 = -KC32;
  constexpr float  DRD32 = (float)(12.0 * RD64);
  constexpr float  ISC32 = (float)(2.0 * RD64 / 45.0);
  constexpr double Q64   = (100.0 - 0.1) / 999.0;     // np.linspace step

  __shared__ __align__(16) float2 tv[3][1000];   // { l(l+1)/r^2 , 1/r }

  for (int t = threadIdx.x; t < 3000; t += 64) {
    int li = t / 1000, i = t - li * 1000;
    double y = (double)i * Q64 + 0.1;
    float r  = (i == 999) ? 100.0f : (float)y;
    float r2 = fmul32(r, r);
    float num = (float)(li * (li + 1));
    tv[li][i] = make_float2(num / r2, 1.0f / r);
  }
  __syncthreads();

  const int tid = blockIdx.x * 64 + threadIdx.x;
  if (tid >= ntot) return;
  const int b = tid / 3;
  const int l = tid - b * 3;
  const float e  = ein[b];
  const float me = -e;
  const float2* __restrict__ tvl = tv[l];

  // rolling state
  float s0, s1, s2, s3;                       // last 4 u (s3 newest)
  float cd1, cd2, cd3, cd4;                   // last 4 d  (cd1 newest)
  float ca1, ca2, ca3;                        // last 3 a
  float cb1, cb2;                             // last 2 b

  auto MKC = [&](float tx, float ty) -> Coef {
    Coef c;
    float f  = fadd32(tx, fsub32(me, ty));
    c.a  = FMA32(KA32, f, 2.0f);
    c.bc = FMA32(KB32, f, -2.0f);
    c.d  = FMA32(nKC32, f, 1.0f);             // d = 1 - KC*f
    float y0 = __builtin_amdgcn_rcpf(c.d);
    float e0 = FMA32(-c.d, y0, 1.0f);
    float y1 = FMA32(y0, e0, y0);
    float e1 = FMA32(-c.d, y1, 1.0f);
    c.y2 = FMA32(y1, e1, y1);
    return c;
  };
  auto WC = [&](float sv, float dold, const Coef& c) -> float {
    float n  = fmul32(sv, dold);
    float q0 = fmul32(n, c.y2);
    float r  = FMA32(-c.d, q0, n);
    return FMA32(r, c.y2, q0);                // == divcr(n, c.d) bitwise
  };
  auto SSTEP = [&](const Coef& c) {
    float w  = WC(s0, cd4, c);
    float m2 = fmul32(s2, cb2);
    float t1 = FMA32(s3, ca1, m2);
    float t2 = FMA32(s1, ca3, -w);
    float u  = fadd32(t1, t2);
    cd4 = cd3; cd3 = cd2; cd2 = cd1; cd1 = c.d;
    ca3 = ca2; ca2 = ca1; ca1 = c.a;
    cb2 = cb1; cb1 = c.bc;
    s0 = s1; s1 = s2; s2 = s3; s3 = u;
  };
  // 4-step group (verified bit-exact r18): w's from entering state, then spine.
  auto G4 = [&](const Coef& e1c, const Coef& e2c, const Coef& e3c, const Coef& e4c,
                float& uo1, float& uo2, float& uo3, float& uo4) {
    float w1 = WC(s0, cd4, e1c);
    float w2 = WC(s1, cd3, e2c);
    float w3 = WC(s2, cd2, e3c);
    float w4 = WC(s3, cd1, e4c);
    float m1 = fmul32(s2, cb2);
    float t11 = FMA32(s3, ca1, m1);
    float t21 = FMA32(s1, ca3, -w1);
    float u1 = fadd32(t11, t21);
    float m2 = fmul32(s3, cb1);
    float t22 = FMA32(s2, ca2, -w2);
    float t12 = FMA32(u1, e1c.a, m2);
    float u2 = fadd32(t12, t22);
    float m3 = fmul32(u1, e1c.bc);
    float t23 = FMA32(s3, ca1, -w3);
    float t13 = FMA32(u2, e2c.a, m3);
    float u3 = fadd32(t13, t23);
    float m4 = fmul32(u2, e2c.bc);
    float t24 = FMA32(u1, e1c.a, -w4);
    float t14 = FMA32(u3, e3c.a, m4);
    float u4 = fadd32(t14, t24);
    cd4 = e1c.d; cd3 = e2c.d; cd2 = e3c.d; cd1 = e4c.d;
    ca3 = e2c.a; ca2 = e3c.a; ca1 = e4c.a;
    cb2 = e3c.bc; cb1 = e4c.bc;
    s0 = u1; s1 = u2; s2 = u3; s3 = u4;
    uo1 = u1; uo2 = u2; uo3 = u3; uo4 = u4;
  };

  auto FVAL = [&](int idx) -> float {
    float2 t_ = tvl[idx];
    return fadd32(t_.x, fsub32(me, t_.y));
  };
  auto SEED = [&](float f0, float f1, float f2v, float f3) {
    ca1 = FMA32(KA32, f3, 2.0f);
    ca2 = FMA32(KA32, f2v, 2.0f);
    ca3 = FMA32(KA32, f1, 2.0f);
    cb1 = FMA32(KB32, f3, -2.0f);
    cb2 = FMA32(KB32, f2v, -2.0f);
    cd1 = FMA32(nKC32, f3, 1.0f);
    cd2 = FMA32(nKC32, f2v, 1.0f);
    cd3 = FMA32(nKC32, f1, 1.0f);
    cd4 = FMA32(nKC32, f0, 1.0f);
  };
  auto PANEL = [&](float f0, float f1, float f2v, float f3, float f4) -> float {
    float s1q = FMA32(f0, f0, fmul32(f4, f4));
    float s3q = FMA32(f1, f1, fmul32(f3, f3));
    float t   = FMA32(7.0f, s1q, fmul32(32.0f, s3q));
    float g   = FMA32(12.0f, f2v, t);
    return fmul32(g, ISC32);
  };
  auto DER5 = [&](float f4, float f3, float f2v, float f1, float f0) -> float {
    float m48 = fmul32(48.0f, f3);
    float d1  = FMA32(25.0f, f4, -m48);
    float d2  = FMA32(36.0f, f2v, d1);
    float d3  = FMA32(-16.0f, f1, d2);
    float d4v = FMA32(3.0f, f0, d3);
    return d4v / DRD32;
  };

  float rr[4];
  #pragma unroll
  for (int i = 0; i < 4; ++i) rr[i] = (float)((double)i * Q64 + 0.1);

  float lf_in, lf_out, integ_in, integ_out, u100v, v899;

  // ====================== forward chain: u_zero, i = 4..100 ==================
  {
    #pragma unroll
    for (int i = 0; i < 4; ++i) {             // powf ~CR via exact fp64 powers
      double rd = (double)rr[i];
      double r2 = rd * rd;
      float p1, p2;
      if (l == 0)      { p1 = rr[i];            p2 = (float)r2;        }
      else if (l == 1) { p1 = (float)r2;        p2 = (float)(r2 * rd); }
      else             { p1 = (float)(r2 * rd); p2 = (float)(r2 * r2); }
      float q  = p2 / (float)(2 * (l + 1));
      float u0 = fsub32(p1, q);
      if (i == 0) s0 = u0; else if (i == 1) s1 = u0; else if (i == 2) s2 = u0; else s3 = u0;
    }
    SEED(FVAL(0), FVAL(1), FVAL(2), FVAL(3));

    float p0 = s0, p1 = s1, p2 = s2, p3 = s3;
    { float2 t4 = tvl[4]; SSTEP(MKC(t4.x, t4.y)); }
    float accI = PANEL(p0, p1, p2, p3, s3);   // panel 0; sequential ascending
    float pb = s3;
    #pragma unroll 2
    for (int k = 1; k < 24; ++k) {
      int base = 4 * k;
      float2 t1v = tvl[base + 1], t2v = tvl[base + 2];
      float2 t3v = tvl[base + 3], t4v = tvl[base + 4];
      Coef c1 = MKC(t1v.x, t1v.y), c2 = MKC(t2v.x, t2v.y);
      Coef c3 = MKC(t3v.x, t3v.y), c4 = MKC(t4v.x, t4v.y);
      float q1, q2, q3, q4;
      G4(c1, c2, c3, c4, q1, q2, q3, q4);
      accI = fadd32(accI, PANEL(pb, q1, q2, q3, q4));
      pb = q4;
    }
    float u96 = pb;
    float2 t97 = tvl[97], t98 = tvl[98], t99 = tvl[99], t100 = tvl[100];
    Coef c97 = MKC(t97.x, t97.y), c98 = MKC(t98.x, t98.y);
    Coef c99 = MKC(t99.x, t99.y), c100 = MKC(t100.x, t100.y);
    float u97, u98, u99;
    SSTEP(c97);  u97 = s3;
    SSTEP(c98);  u98 = s3;
    SSTEP(c99);  u99 = s3;
    SSTEP(c100); u100v = s3;
    integ_in = accI;
    lf_in = DER5(u100v, u99, u98, u97, u96) / u100v;
  }

  // =============== backward chain: v[j], j=4..999, factor idx 999-j ==========
  // u_infty index m = 999-j runs 995..0 in 249 groups of 4 (m0 = 992-4g).
  // Depth-1 software pipeline: load g+2 | MKC g+1 | WC+spine g | panel.
  // Groups g=0..24: no panel (m>896). Panels p = 248-g for g>=25, descending
  // production order (validated r16-r18). Captures: g=223 -> v899=u[100];
  // g=224 -> v900..v903 = u[99..96].
  {
    float sq = (float)sqrt((double)fabsf(e));
    #pragma unroll
    for (int i = 0; i < 4; ++i) {
      float x    = fmul32(rr[i], sq);
      float xl   = (l == 0) ? 1.0f : ((l == 1) ? x : fmul32(x, x));
      float fact = (l == 0) ? 1.0f : ((l == 1) ? 3.0f : 15.0f);
      float base = xl / fact;
      float h  = fmul32(x, x) / 2.0f;
      float c1 = (float)(2 * l + 3);
      float c2 = (float)(2 * (2 * l + 3) * (2 * l + 5));
      float t2 = fadd32(1.0f, h / c1);
      float series = fadd32(t2, fmul32(h, h) / c2);
      float ui = fmul32(fmul32(rr[i], base), series);
      if (i == 0) s0 = ui; else if (i == 1) s1 = ui; else if (i == 2) s2 = ui; else s3 = ui;
    }
    SEED(FVAL(999), FVAL(998), FVAL(997), FVAL(996));

    // pipeline prologue: Ccur = MKC(group 0); L = loads(group 1)
    float4 alo = *(const float4*)&tvl[992];
    float4 ahi = *(const float4*)&tvl[994];
    Coef c1 = MKC(ahi.z, ahi.w), c2 = MKC(ahi.x, ahi.y);
    Coef c3 = MKC(alo.z, alo.w), c4 = MKC(alo.x, alo.y);
    float4 Llo = *(const float4*)&tvl[988];
    float4 Lhi = *(const float4*)&tvl[990];

    float accO = 0.0f, r4v = 0.0f;
    float v900, v901, v902, v903;
    v899 = 0.0f; v900 = v901 = v902 = v903 = 0.0f;

    for (int g = 0; g < 249; ++g) {
      // (a) loads for group g+2
      float4 Nlo, Nhi;
      if (g < 247) {
        int m2a = 992 - 4 * (g + 2);
        Nlo = *(const float4*)&tvl[m2a];
        Nhi = *(const float4*)&tvl[m2a + 2];
      }
      // (b) MKC for group g+1 — independent of chain state
      Coef n1, n2, n3, n4;
      if (g < 248) {
        n1 = MKC(Lhi.z, Lhi.w); n2 = MKC(Lhi.x, Lhi.y);
        n3 = MKC(Llo.z, Llo.w); n4 = MKC(Llo.x, Llo.y);
      }
      // (c) WC + spine for group g
      float u1, u2, u3, u4;
      G4(c1, c2, c3, c4, u1, u2, u3, u4);
      // (d) panel accumulation (descending production order)
      if (g >= 25) {
        accO = fadd32(accO, PANEL(u4, u3, u2, u1, r4v));
        if (g == 223) v899 = u4;                       // u_infty[100]
        if (g == 224) { v900 = u1; v901 = u2; v902 = u3; v903 = u4; }
      }
      r4v = u4;
      if (g < 248) {
        c1 = n1; c2 = n2; c3 = n3; c4 = n4;
        Llo = Nlo; Lhi = Nhi;
      }
    }

    integ_out = accO;
    lf_out = DER5(v899, v900, v901, v902, v903) / v899;
  }

  // ======= final combine, fp32 in reference order =======
  float uzsq = fmul32(u100v, u100v);
  float uisq = fmul32(v899, v899);
  float den  = fadd32(integ_in / uzsq, integ_out / uisq);
  float dnum = fsub32(lf_out, lf_in);
  float delta = (-dnum) / den;
  out[tid] = fadd32(e, delta);
}

extern "C" void kernel_launch(void* const* d_in, const int* in_sizes, int n_in,
                              void* d_out, int out_size, void* d_ws, size_t ws_size,
                              hipStream_t stream) {
  const float* ein = (const float*)d_in[0];
  float* out = (float*)d_out;
  int ntot = in_sizes[0] * 3;             // 4096 energies x 3 l-values
  int grid = (ntot + 63) / 64;            // 192 blocks, 1 problem/thread
  eval_eig_kernel<<<dim3(grid), dim3(64), 0, stream>>>(ein, out, ntot);
}

// Round 20
// 61.826 us; speedup vs baseline: 1.1385x; 1.1385x over previous
//
#include <hip/hip_runtime.h>
#include <math.h>

#pragma clang fp contract(off)

// ---------------------------------------------------------------------------
// Bit-exact fp32 emulation of the XLA-CPU (reassoc+contract) reference
// realization — PASSING since r10 (absmax 0.1875, bit-stable r10-r19).
// Per-step value tree (unchanged since r10):
//   u = fadd( fma(s3,a1, mul(s2,b2)), fma(s1,a3, -w) ),
//   w = Markstein(n=mul(s0,d4), d, y2),  y2 = rcp+2xNewton(d)  [VCC-free CR]
// r19 lesson: the rolled unified loop's runtime branches cost 17%; r18's
// segment-structured unrolled loops already expose the pipeline to the
// scheduler. This round = r18 verbatim with backward unroll 2 -> 4 (wider
// cross-group window; ~3KB body, no I$ risk). Same op set => same bits.
// ---------------------------------------------------------------------------

__device__ __forceinline__ float fmul32(float a, float b) { return a * b; }
__device__ __forceinline__ float fadd32(float a, float b) { return a + b; }
__device__ __forceinline__ float fsub32(float a, float b) { return a - b; }
#define FMA32(a, b, c) __builtin_fmaf((a), (b), (c))

struct Coef { float a, bc, d, y2; };

__global__ __launch_bounds__(64, 1)
void eval_eig_kernel(const float* __restrict__ ein, float* __restrict__ out, int ntot) {
  constexpr double RD64  = 100.0 / 1000.0;
  constexpr double RD2   = RD64 * RD64;
  constexpr float  KA32  = (float)(13.0 / 15.0 * RD2);
  constexpr float  KB32  = (float)( 7.0 / 60.0 * RD2);
  constexpr float  KC32  = (float)( 3.0 / 40.0 * RD2);
  constexpr float  nKC32 = -KC32;
  constexpr float  DRD32 = (float)(12.0 * RD64);
  constexpr float  ISC32 = (float)(2.0 * RD64 / 45.0);
  constexpr double Q64   = (100.0 - 0.1) / 999.0;     // np.linspace step

  __shared__ __align__(16) float2 tv[3][1000];   // { l(l+1)/r^2 , 1/r }

  for (int t = threadIdx.x; t < 3000; t += 64) {
    int li = t / 1000, i = t - li * 1000;
    double y = (double)i * Q64 + 0.1;
    float r  = (i == 999) ? 100.0f : (float)y;
    float r2 = fmul32(r, r);
    float num = (float)(li * (li + 1));
    tv[li][i] = make_float2(num / r2, 1.0f / r);
  }
  __syncthreads();

  const int tid = blockIdx.x * 64 + threadIdx.x;
  if (tid >= ntot) return;
  const int b = tid / 3;
  const int l = tid - b * 3;
  const float e  = ein[b];
  const float me = -e;
  const float2* __restrict__ tvl = tv[l];

  // rolling state (explicit; groups use SSA form internally)
  float s0, s1, s2, s3;                       // last 4 u (s3 newest)
  float cd1, cd2, cd3, cd4;                   // last 4 d  (cd1 newest)
  float ca1, ca2, ca3;                        // last 3 a
  float cb1, cb2;                             // last 2 b

  auto MKC = [&](float tx, float ty) -> Coef {
    Coef c;
    float f  = fadd32(tx, fsub32(me, ty));
    c.a  = FMA32(KA32, f, 2.0f);
    c.bc = FMA32(KB32, f, -2.0f);
    c.d  = FMA32(nKC32, f, 1.0f);             // d = 1 - KC*f
    float y0 = __builtin_amdgcn_rcpf(c.d);
    float e0 = FMA32(-c.d, y0, 1.0f);
    float y1 = FMA32(y0, e0, y0);
    float e1 = FMA32(-c.d, y1, 1.0f);
    c.y2 = FMA32(y1, e1, y1);
    return c;
  };
  auto WC = [&](float sv, float dold, const Coef& c) -> float {
    float n  = fmul32(sv, dold);
    float q0 = fmul32(n, c.y2);
    float r  = FMA32(-c.d, q0, n);
    return FMA32(r, c.y2, q0);                // == divcr(n, c.d) bitwise
  };
  // boundary single step (identical value tree)
  auto SSTEP = [&](const Coef& c) {
    float w  = WC(s0, cd4, c);
    float m2 = fmul32(s2, cb2);
    float t1 = FMA32(s3, ca1, m2);
    float t2 = FMA32(s1, ca3, -w);
    float u  = fadd32(t1, t2);
    cd4 = cd3; cd3 = cd2; cd2 = cd1; cd1 = c.d;
    ca3 = ca2; ca2 = ca1; ca1 = c.a;
    cb2 = cb1; cb1 = c.bc;
    s0 = s1; s1 = s2; s2 = s3; s3 = u;
  };
  // 4-step group, software-pipelined (verified bit-exact r18/r19).
  auto G4 = [&](const Coef& e1c, const Coef& e2c, const Coef& e3c, const Coef& e4c,
                float& uo1, float& uo2, float& uo3, float& uo4) {
    float w1 = WC(s0, cd4, e1c);
    float w2 = WC(s1, cd3, e2c);
    float w3 = WC(s2, cd2, e3c);
    float w4 = WC(s3, cd1, e4c);
    float m1 = fmul32(s2, cb2);
    float t11 = FMA32(s3, ca1, m1);
    float t21 = FMA32(s1, ca3, -w1);
    float u1 = fadd32(t11, t21);
    float m2 = fmul32(s3, cb1);
    float t22 = FMA32(s2, ca2, -w2);
    float t12 = FMA32(u1, e1c.a, m2);
    float u2 = fadd32(t12, t22);
    float m3 = fmul32(u1, e1c.bc);
    float t23 = FMA32(s3, ca1, -w3);
    float t13 = FMA32(u2, e2c.a, m3);
    float u3 = fadd32(t13, t23);
    float m4 = fmul32(u2, e2c.bc);
    float t24 = FMA32(u1, e1c.a, -w4);
    float t14 = FMA32(u3, e3c.a, m4);
    float u4 = fadd32(t14, t24);
    cd4 = e1c.d; cd3 = e2c.d; cd2 = e3c.d; cd1 = e4c.d;
    ca3 = e2c.a; ca2 = e3c.a; ca1 = e4c.a;
    cb2 = e3c.bc; cb1 = e4c.bc;
    s0 = u1; s1 = u2; s2 = u3; s3 = u4;
    uo1 = u1; uo2 = u2; uo3 = u3; uo4 = u4;
  };

  auto FVAL = [&](int idx) -> float {
    float2 t_ = tvl[idx];
    return fadd32(t_.x, fsub32(me, t_.y));
  };
  auto SEED = [&](float f0, float f1, float f2v, float f3) {
    ca1 = FMA32(KA32, f3, 2.0f);
    ca2 = FMA32(KA32, f2v, 2.0f);
    ca3 = FMA32(KA32, f1, 2.0f);
    cb1 = FMA32(KB32, f3, -2.0f);
    cb2 = FMA32(KB32, f2v, -2.0f);
    cd1 = FMA32(nKC32, f3, 1.0f);
    cd2 = FMA32(nKC32, f2v, 1.0f);
    cd3 = FMA32(nKC32, f1, 1.0f);
    cd4 = FMA32(nKC32, f0, 1.0f);
  };
  auto PANEL = [&](float f0, float f1, float f2v, float f3, float f4) -> float {
    float s1q = FMA32(f0, f0, fmul32(f4, f4));
    float s3q = FMA32(f1, f1, fmul32(f3, f3));
    float t   = FMA32(7.0f, s1q, fmul32(32.0f, s3q));
    float g   = FMA32(12.0f, f2v, t);
    return fmul32(g, ISC32);
  };
  auto DER5 = [&](float f4, float f3, float f2v, float f1, float f0) -> float {
    float m48 = fmul32(48.0f, f3);
    float d1  = FMA32(25.0f, f4, -m48);
    float d2  = FMA32(36.0f, f2v, d1);
    float d3  = FMA32(-16.0f, f1, d2);
    float d4v = FMA32(3.0f, f0, d3);
    return d4v / DRD32;
  };

  float rr[4];
  #pragma unroll
  for (int i = 0; i < 4; ++i) rr[i] = (float)((double)i * Q64 + 0.1);

  float lf_in, lf_out, integ_in, integ_out, u100v, v899;

  // ====================== forward chain: u_zero, i = 4..100 ==================
  {
    #pragma unroll
    for (int i = 0; i < 4; ++i) {             // powf ~CR via exact fp64 powers
      double rd = (double)rr[i];
      double r2 = rd * rd;
      float p1, p2;
      if (l == 0)      { p1 = rr[i];            p2 = (float)r2;        }
      else if (l == 1) { p1 = (float)r2;        p2 = (float)(r2 * rd); }
      else             { p1 = (float)(r2 * rd); p2 = (float)(r2 * r2); }
      float q  = p2 / (float)(2 * (l + 1));
      float u0 = fsub32(p1, q);
      if (i == 0) s0 = u0; else if (i == 1) s1 = u0; else if (i == 2) s2 = u0; else s3 = u0;
    }
    SEED(FVAL(0), FVAL(1), FVAL(2), FVAL(3));

    float p0 = s0, p1 = s1, p2 = s2, p3 = s3;
    { float2 t4 = tvl[4]; SSTEP(MKC(t4.x, t4.y)); }
    float accI = PANEL(p0, p1, p2, p3, s3);   // panel 0; sequential ascending
    float pb = s3;
    #pragma unroll 2
    for (int k = 1; k < 24; ++k) {
      int base = 4 * k;
      float2 t1v = tvl[base + 1], t2v = tvl[base + 2];
      float2 t3v = tvl[base + 3], t4v = tvl[base + 4];
      Coef c1 = MKC(t1v.x, t1v.y), c2 = MKC(t2v.x, t2v.y);
      Coef c3 = MKC(t3v.x, t3v.y), c4 = MKC(t4v.x, t4v.y);
      float q1, q2, q3, q4;
      G4(c1, c2, c3, c4, q1, q2, q3, q4);
      accI = fadd32(accI, PANEL(pb, q1, q2, q3, q4));
      pb = q4;
    }
    float u96 = pb;
    float2 t97 = tvl[97], t98 = tvl[98], t99 = tvl[99], t100 = tvl[100];
    Coef c97 = MKC(t97.x, t97.y), c98 = MKC(t98.x, t98.y);
    Coef c99 = MKC(t99.x, t99.y), c100 = MKC(t100.x, t100.y);
    float u97, u98, u99;
    SSTEP(c97);  u97 = s3;
    SSTEP(c98);  u98 = s3;
    SSTEP(c99);  u99 = s3;
    SSTEP(c100); u100v = s3;
    integ_in = accI;
    lf_in = DER5(u100v, u99, u98, u97, u96) / u100v;
  }

  // =============== backward chain: v[j], j=4..999, factor idx 999-j ==========
  // u_infty index m = 999-j runs 995..0; 4-step groups descending. Panels
  // accumulate in production (descending) order — validated r16-r19.
  {
    float sq = (float)sqrt((double)fabsf(e));
    #pragma unroll
    for (int i = 0; i < 4; ++i) {
      float x    = fmul32(rr[i], sq);
      float xl   = (l == 0) ? 1.0f : ((l == 1) ? x : fmul32(x, x));
      float fact = (l == 0) ? 1.0f : ((l == 1) ? 3.0f : 15.0f);
      float base = xl / fact;
      float h  = fmul32(x, x) / 2.0f;
      float c1 = (float)(2 * l + 3);
      float c2 = (float)(2 * (2 * l + 3) * (2 * l + 5));
      float t2 = fadd32(1.0f, h / c1);
      float series = fadd32(t2, fmul32(h, h) / c2);
      float ui = fmul32(fmul32(rr[i], base), series);
      if (i == 0) s0 = ui; else if (i == 1) s1 = ui; else if (i == 2) s2 = ui; else s3 = ui;
    }
    SEED(FVAL(999), FVAL(998), FVAL(997), FVAL(996));

    // Segment A: m = 995..896 (25 groups of 4, descending within group).
    float4 lo = *(const float4*)&tvl[992];
    float4 hi = *(const float4*)&tvl[994];
    #pragma unroll 4
    for (int g = 0; g < 25; ++g) {
      Coef e1c = MKC(hi.z, hi.w), e2c = MKC(hi.x, hi.y);
      Coef e3c = MKC(lo.z, lo.w), e4c = MKC(lo.x, lo.y);
      if (g < 24) {                           // prefetch next group
        int m0 = 992 - 4 * (g + 1);
        lo = *(const float4*)&tvl[m0];
        hi = *(const float4*)&tvl[m0 + 2];
      }
      float x1, x2, x3, x4;
      G4(e1c, e2c, e3c, e4c, x1, x2, x3, x4);
    }
    float r4v = s3;                           // u[896] opens panel 223
    float accO = 0.0f;

    float v900, v901, v902, v903;
    lo = *(const float4*)&tvl[4 * 223];
    hi = *(const float4*)&tvl[4 * 223 + 2];
    // Panel group macro: steps m=4p+3..4p, close panel p, hand f0 to next.
    #define BGROUP(P)                                                          \
      Coef e1c = MKC(hi.z, hi.w), e2c = MKC(hi.x, hi.y);                       \
      Coef e3c = MKC(lo.z, lo.w), e4c = MKC(lo.x, lo.y);                       \
      if ((P) > 0) {                                                           \
        lo = *(const float4*)&tvl[4 * (P) - 4];                                \
        hi = *(const float4*)&tvl[4 * (P) - 2];                                \
      }                                                                        \
      float f3v, f2w, f1v, f0v;                                                \
      G4(e1c, e2c, e3c, e4c, f3v, f2w, f1v, f0v);                              \
      accO = fadd32(accO, PANEL(f0v, f1v, f2w, f3v, r4v));                     \
      r4v = f0v;

    // Segment B1: panels 223..26
    #pragma unroll 4
    for (int p = 223; p >= 26; --p) { BGROUP(p); }
    // Panel 25: f0 = u[100] = u_infty[MR]
    { BGROUP(25); v899 = f0v; }
    // Panel 24: f3..f0 = u[99], u[98], u[97], u[96]
    { BGROUP(24); v900 = f3v; v901 = f2w; v902 = f1v; v903 = f0v; }
    // Segment B2: panels 23..0
    #pragma unroll 4
    for (int p = 23; p >= 0; --p) { BGROUP(p); }
    #undef BGROUP

    integ_out = accO;
    lf_out = DER5(v899, v900, v901, v902, v903) / v899;
  }

  // ======= final combine, fp32 in reference order =======
  float uzsq = fmul32(u100v, u100v);
  float uisq = fmul32(v899, v899);
  float den  = fadd32(integ_in / uzsq, integ_out / uisq);
  float dnum = fsub32(lf_out, lf_in);
  float delta = (-dnum) / den;
  out[tid] = fadd32(e, delta);
}

extern "C" void kernel_launch(void* const* d_in, const int* in_sizes, int n_in,
                              void* d_out, int out_size, void* d_ws, size_t ws_size,
                              hipStream_t stream) {
  const float* ein = (const float*)d_in[0];
  float* out = (float*)d_out;
  int ntot = in_sizes[0] * 3;             // 4096 energies x 3 l-values
  int grid = (ntot + 63) / 64;            // 192 blocks, 1 problem/thread
  eval_eig_kernel<<<dim3(grid), dim3(64), 0, stream>>>(ein, out, ntot);
}

// Round 21
// 60.130 us; speedup vs baseline: 1.1706x; 1.0282x over previous
//
#include <hip/hip_runtime.h>
#include <math.h>

#pragma clang fp contract(off)

// ---------------------------------------------------------------------------
// FINAL KERNEL (r18 build, best measured: 60.3us, absmax 0.1875 < 0.2925).
// Bit-exact fp32 emulation of the XLA-CPU (reassoc+contract) reference
// realization — PASSING since r10, bit-stable across r10-r20.
// Per-step value tree:
//   u = fadd( fma(s3,a1, mul(s2,b2)), fma(s1,a3, -w) ),
//   w = Markstein(n=mul(s0,d4), d, y2),  y2 = rcp+2xNewton(d)  [VCC-free CR]
// Structure: 192 blocks x 64 thr (1 problem/thread = the problem's full
// parallelism: 192 waves), LDS coefficient table, branch-free 4-step groups
// with software-pipelined divides (G4), descending backward panel-sum
// (validated r16+), occupancy-1 launch bounds.
// Structural floor: 996 serial bit-exact fp32 steps/problem; active SIMDs
// issue ~70% of cycles; 2-prob/thread & wave-concentration both regress.
// ---------------------------------------------------------------------------

__device__ __forceinline__ float fmul32(float a, float b) { return a * b; }
__device__ __forceinline__ float fadd32(float a, float b) { return a + b; }
__device__ __forceinline__ float fsub32(float a, float b) { return a - b; }
#define FMA32(a, b, c) __builtin_fmaf((a), (b), (c))

struct Coef { float a, bc, d, y2; };

__global__ __launch_bounds__(64, 1)
void eval_eig_kernel(const float* __restrict__ ein, float* __restrict__ out, int ntot) {
  constexpr double RD64  = 100.0 / 1000.0;
  constexpr double RD2   = RD64 * RD64;
  constexpr float  KA32  = (float)(13.0 / 15.0 * RD2);
  constexpr float  KB32  = (float)( 7.0 / 60.0 * RD2);
  constexpr float  KC32  = (float)( 3.0 / 40.0 * RD2);
  constexpr float  nKC32 = -KC32;
  constexpr float  DRD32 = (float)(12.0 * RD64);
  constexpr float  ISC32 = (float)(2.0 * RD64 / 45.0);
  constexpr double Q64   = (100.0 - 0.1) / 999.0;     // np.linspace step

  __shared__ __align__(16) float2 tv[3][1000];   // { l(l+1)/r^2 , 1/r }

  for (int t = threadIdx.x; t < 3000; t += 64) {
    int li = t / 1000, i = t - li * 1000;
    double y = (double)i * Q64 + 0.1;
    float r  = (i == 999) ? 100.0f : (float)y;
    float r2 = fmul32(r, r);
    float num = (float)(li * (li + 1));
    tv[li][i] = make_float2(num / r2, 1.0f / r);
  }
  __syncthreads();

  const int tid = blockIdx.x * 64 + threadIdx.x;
  if (tid >= ntot) return;
  const int b = tid / 3;
  const int l = tid - b * 3;
  const float e  = ein[b];
  const float me = -e;
  const float2* __restrict__ tvl = tv[l];

  // rolling state (explicit; groups use SSA form internally)
  float s0, s1, s2, s3;                       // last 4 u (s3 newest)
  float cd1, cd2, cd3, cd4;                   // last 4 d  (cd1 newest)
  float ca1, ca2, ca3;                        // last 3 a
  float cb1, cb2;                             // last 2 b

  auto MKC = [&](float tx, float ty) -> Coef {
    Coef c;
    float f  = fadd32(tx, fsub32(me, ty));
    c.a  = FMA32(KA32, f, 2.0f);
    c.bc = FMA32(KB32, f, -2.0f);
    c.d  = FMA32(nKC32, f, 1.0f);             // d = 1 - KC*f
    float y0 = __builtin_amdgcn_rcpf(c.d);
    float e0 = FMA32(-c.d, y0, 1.0f);
    float y1 = FMA32(y0, e0, y0);
    float e1 = FMA32(-c.d, y1, 1.0f);
    c.y2 = FMA32(y1, e1, y1);
    return c;
  };
  auto WC = [&](float sv, float dold, const Coef& c) -> float {
    float n  = fmul32(sv, dold);
    float q0 = fmul32(n, c.y2);
    float r  = FMA32(-c.d, q0, n);
    return FMA32(r, c.y2, q0);                // == divcr(n, c.d) bitwise
  };
  // boundary single step (identical value tree)
  auto SSTEP = [&](const Coef& c) {
    float w  = WC(s0, cd4, c);
    float m2 = fmul32(s2, cb2);
    float t1 = FMA32(s3, ca1, m2);
    float t2 = FMA32(s1, ca3, -w);
    float u  = fadd32(t1, t2);
    cd4 = cd3; cd3 = cd2; cd2 = cd1; cd1 = c.d;
    ca3 = ca2; ca2 = ca1; ca1 = c.a;
    cb2 = cb1; cb1 = c.bc;
    s0 = s1; s1 = s2; s2 = s3; s3 = u;
  };
  // 4-step group, software-pipelined (verified bit-exact r18-r20).
  auto G4 = [&](const Coef& e1c, const Coef& e2c, const Coef& e3c, const Coef& e4c,
                float& uo1, float& uo2, float& uo3, float& uo4) {
    float w1 = WC(s0, cd4, e1c);
    float w2 = WC(s1, cd3, e2c);
    float w3 = WC(s2, cd2, e3c);
    float w4 = WC(s3, cd1, e4c);
    float m1 = fmul32(s2, cb2);
    float t11 = FMA32(s3, ca1, m1);
    float t21 = FMA32(s1, ca3, -w1);
    float u1 = fadd32(t11, t21);
    float m2 = fmul32(s3, cb1);
    float t22 = FMA32(s2, ca2, -w2);
    float t12 = FMA32(u1, e1c.a, m2);
    float u2 = fadd32(t12, t22);
    float m3 = fmul32(u1, e1c.bc);
    float t23 = FMA32(s3, ca1, -w3);
    float t13 = FMA32(u2, e2c.a, m3);
    float u3 = fadd32(t13, t23);
    float m4 = fmul32(u2, e2c.bc);
    float t24 = FMA32(u1, e1c.a, -w4);
    float t14 = FMA32(u3, e3c.a, m4);
    float u4 = fadd32(t14, t24);
    cd4 = e1c.d; cd3 = e2c.d; cd2 = e3c.d; cd1 = e4c.d;
    ca3 = e2c.a; ca2 = e3c.a; ca1 = e4c.a;
    cb2 = e3c.bc; cb1 = e4c.bc;
    s0 = u1; s1 = u2; s2 = u3; s3 = u4;
    uo1 = u1; uo2 = u2; uo3 = u3; uo4 = u4;
  };

  auto FVAL = [&](int idx) -> float {
    float2 t_ = tvl[idx];
    return fadd32(t_.x, fsub32(me, t_.y));
  };
  auto SEED = [&](float f0, float f1, float f2v, float f3) {
    ca1 = FMA32(KA32, f3, 2.0f);
    ca2 = FMA32(KA32, f2v, 2.0f);
    ca3 = FMA32(KA32, f1, 2.0f);
    cb1 = FMA32(KB32, f3, -2.0f);
    cb2 = FMA32(KB32, f2v, -2.0f);
    cd1 = FMA32(nKC32, f3, 1.0f);
    cd2 = FMA32(nKC32, f2v, 1.0f);
    cd3 = FMA32(nKC32, f1, 1.0f);
    cd4 = FMA32(nKC32, f0, 1.0f);
  };
  auto PANEL = [&](float f0, float f1, float f2v, float f3, float f4) -> float {
    float s1q = FMA32(f0, f0, fmul32(f4, f4));
    float s3q = FMA32(f1, f1, fmul32(f3, f3));
    float t   = FMA32(7.0f, s1q, fmul32(32.0f, s3q));
    float g   = FMA32(12.0f, f2v, t);
    return fmul32(g, ISC32);
  };
  auto DER5 = [&](float f4, float f3, float f2v, float f1, float f0) -> float {
    float m48 = fmul32(48.0f, f3);
    float d1  = FMA32(25.0f, f4, -m48);
    float d2  = FMA32(36.0f, f2v, d1);
    float d3  = FMA32(-16.0f, f1, d2);
    float d4v = FMA32(3.0f, f0, d3);
    return d4v / DRD32;
  };

  float rr[4];
  #pragma unroll
  for (int i = 0; i < 4; ++i) rr[i] = (float)((double)i * Q64 + 0.1);

  float lf_in, lf_out, integ_in, integ_out, u100v, v899;

  // ====================== forward chain: u_zero, i = 4..100 ==================
  {
    #pragma unroll
    for (int i = 0; i < 4; ++i) {             // powf ~CR via exact fp64 powers
      double rd = (double)rr[i];
      double r2 = rd * rd;
      float p1, p2;
      if (l == 0)      { p1 = rr[i];            p2 = (float)r2;        }
      else if (l == 1) { p1 = (float)r2;        p2 = (float)(r2 * rd); }
      else             { p1 = (float)(r2 * rd); p2 = (float)(r2 * r2); }
      float q  = p2 / (float)(2 * (l + 1));
      float u0 = fsub32(p1, q);
      if (i == 0) s0 = u0; else if (i == 1) s1 = u0; else if (i == 2) s2 = u0; else s3 = u0;
    }
    SEED(FVAL(0), FVAL(1), FVAL(2), FVAL(3));

    float p0 = s0, p1 = s1, p2 = s2, p3 = s3;
    { float2 t4 = tvl[4]; SSTEP(MKC(t4.x, t4.y)); }
    float accI = PANEL(p0, p1, p2, p3, s3);   // panel 0; sequential ascending
    float pb = s3;
    #pragma unroll 2
    for (int k = 1; k < 24; ++k) {
      int base = 4 * k;
      float2 t1v = tvl[base + 1], t2v = tvl[base + 2];
      float2 t3v = tvl[base + 3], t4v = tvl[base + 4];
      Coef c1 = MKC(t1v.x, t1v.y), c2 = MKC(t2v.x, t2v.y);
      Coef c3 = MKC(t3v.x, t3v.y), c4 = MKC(t4v.x, t4v.y);
      float q1, q2, q3, q4;
      G4(c1, c2, c3, c4, q1, q2, q3, q4);
      accI = fadd32(accI, PANEL(pb, q1, q2, q3, q4));
      pb = q4;
    }
    float u96 = pb;
    float2 t97 = tvl[97], t98 = tvl[98], t99 = tvl[99], t100 = tvl[100];
    Coef c97 = MKC(t97.x, t97.y), c98 = MKC(t98.x, t98.y);
    Coef c99 = MKC(t99.x, t99.y), c100 = MKC(t100.x, t100.y);
    float u97, u98, u99;
    SSTEP(c97);  u97 = s3;
    SSTEP(c98);  u98 = s3;
    SSTEP(c99);  u99 = s3;
    SSTEP(c100); u100v = s3;
    integ_in = accI;
    lf_in = DER5(u100v, u99, u98, u97, u96) / u100v;
  }

  // =============== backward chain: v[j], j=4..999, factor idx 999-j ==========
  // u_infty index m = 999-j runs 995..0; 4-step groups descending. Panels
  // accumulate in production (descending) order — validated r16-r20.
  {
    float sq = (float)sqrt((double)fabsf(e));
    #pragma unroll
    for (int i = 0; i < 4; ++i) {
      float x    = fmul32(rr[i], sq);
      float xl   = (l == 0) ? 1.0f : ((l == 1) ? x : fmul32(x, x));
      float fact = (l == 0) ? 1.0f : ((l == 1) ? 3.0f : 15.0f);
      float base = xl / fact;
      float h  = fmul32(x, x) / 2.0f;
      float c1 = (float)(2 * l + 3);
      float c2 = (float)(2 * (2 * l + 3) * (2 * l + 5));
      float t2 = fadd32(1.0f, h / c1);
      float series = fadd32(t2, fmul32(h, h) / c2);
      float ui = fmul32(fmul32(rr[i], base), series);
      if (i == 0) s0 = ui; else if (i == 1) s1 = ui; else if (i == 2) s2 = ui; else s3 = ui;
    }
    SEED(FVAL(999), FVAL(998), FVAL(997), FVAL(996));

    // Segment A: m = 995..896 (25 groups of 4, descending within group).
    float4 lo = *(const float4*)&tvl[992];
    float4 hi = *(const float4*)&tvl[994];
    #pragma unroll 2
    for (int g = 0; g < 25; ++g) {
      Coef e1c = MKC(hi.z, hi.w), e2c = MKC(hi.x, hi.y);
      Coef e3c = MKC(lo.z, lo.w), e4c = MKC(lo.x, lo.y);
      if (g < 24) {                           // prefetch next group
        int m0 = 992 - 4 * (g + 1);
        lo = *(const float4*)&tvl[m0];
        hi = *(const float4*)&tvl[m0 + 2];
      }
      float x1, x2, x3, x4;
      G4(e1c, e2c, e3c, e4c, x1, x2, x3, x4);
    }
    float r4v = s3;                           // u[896] opens panel 223
    float accO = 0.0f;

    float v900, v901, v902, v903;
    lo = *(const float4*)&tvl[4 * 223];
    hi = *(const float4*)&tvl[4 * 223 + 2];
    // Panel group macro: steps m=4p+3..4p, close panel p, hand f0 to next.
    #define BGROUP(P)                                                          \
      Coef e1c = MKC(hi.z, hi.w), e2c = MKC(hi.x, hi.y);                       \
      Coef e3c = MKC(lo.z, lo.w), e4c = MKC(lo.x, lo.y);                       \
      if ((P) > 0) {                                                           \
        lo = *(const float4*)&tvl[4 * (P) - 4];                                \
        hi = *(const float4*)&tvl[4 * (P) - 2];                                \
      }                                                                        \
      float f3v, f2w, f1v, f0v;                                                \
      G4(e1c, e2c, e3c, e4c, f3v, f2w, f1v, f0v);                              \
      accO = fadd32(accO, PANEL(f0v, f1v, f2w, f3v, r4v));                     \
      r4v = f0v;

    // Segment B1: panels 223..26
    #pragma unroll 2
    for (int p = 223; p >= 26; --p) { BGROUP(p); }
    // Panel 25: f0 = u[100] = u_infty[MR]
    { BGROUP(25); v899 = f0v; }
    // Panel 24: f3..f0 = u[99], u[98], u[97], u[96]
    { BGROUP(24); v900 = f3v; v901 = f2w; v902 = f1v; v903 = f0v; }
    // Segment B2: panels 23..0
    #pragma unroll 2
    for (int p = 23; p >= 0; --p) { BGROUP(p); }
    #undef BGROUP

    integ_out = accO;
    lf_out = DER5(v899, v900, v901, v902, v903) / v899;
  }

  // ======= final combine, fp32 in reference order =======
  float uzsq = fmul32(u100v, u100v);
  float uisq = fmul32(v899, v899);
  float den  = fadd32(integ_in / uzsq, integ_out / uisq);
  float dnum = fsub32(lf_out, lf_in);
  float delta = (-dnum) / den;
  out[tid] = fadd32(e, delta);
}

extern "C" void kernel_launch(void* const* d_in, const int* in_sizes, int n_in,
                              void* d_out, int out_size, void* d_ws, size_t ws_size,
                              hipStream_t stream) {
  const float* ein = (const float*)d_in[0];
  float* out = (float*)d_out;
  int ntot = in_sizes[0] * 3;             // 4096 energies x 3 l-values
  int grid = (ntot + 63) / 64;            // 192 blocks, 1 problem/thread
  eval_eig_kernel<<<dim3(grid), dim3(64), 0, stream>>>(ein, out, ntot);
}